// Round 1
// baseline (181.147 us; speedup 1.0000x reference)
//
#include <hip/hip_runtime.h>

// DMoE (PLE/CGC) fused kernel for MI355X (gfx950).
// B=32768, D_IN=256, H=128, N_TASK=2, N_EXP=4, N_SHARE=4.
//
// Strategy:
//   prep_kernel: W_share/W_task/W_gate (f32, k-major) -> WT (bf16, h-major
//                "B^T" layout) in d_ws, so MFMA B-fragments are contiguous.
//   dmoe_main:   512 blocks x 256 thr, 64 rows/block. x tile in LDS (bf16,
//                padded stride 264 to keep ds_read_b128 at 2-way bank alias).
//                Wave w owns h-slice [32w,32w+32): holds W[e] slice in regs,
//                streams A-frags from LDS, accumulates gate-weighted towers
//                for both tasks in registers, writes out.

#define BM 64

typedef __attribute__((ext_vector_type(8))) short short8;   // 8 x bf16 frag
typedef __attribute__((ext_vector_type(4))) float float4v;  // C/D frag

__device__ __forceinline__ unsigned short f2bf(float f) {
  unsigned u = __builtin_bit_cast(unsigned, f);
  u += 0x7FFFu + ((u >> 16) & 1u);   // round-to-nearest-even
  return (unsigned short)(u >> 16);
}

// ---------------------------------------------------------------------------
// Prep: build WT (bf16) in workspace.
//   WT[e][h][k], e = 0..3 shared, 4..11 task (t*4+ee), each 128x256.
//   Then WTg[n][k], n = t*8+g, 16x256, at offset 12*32768.
// Total = 397312 elems = 1552 * 256.
__global__ void prep_kernel(const float* __restrict__ Ws,
                            const float* __restrict__ Wt,
                            const float* __restrict__ Wg,
                            unsigned short* __restrict__ WT) {
  int i = blockIdx.x * 256 + threadIdx.x;
  if (i < 12 * 32768) {
    int e = i >> 15;          // expert
    int r = i & 32767;        // h*256 + k
    int h = r >> 8;
    int k = r & 255;
    const float* src = (e < 4) ? (Ws + ((size_t)e << 15))
                               : (Wt + ((size_t)(e - 4) << 15));
    WT[i] = f2bf(src[k * 128 + h]);   // src is [k][h]
  } else {
    int j = i - 12 * 32768;   // n*256 + k
    int n = j >> 8;
    int k = j & 255;
    int t = n >> 3, g = n & 7;
    WT[i] = f2bf(Wg[(t * 256 + k) * 8 + g]);  // Wg is [t][k][g]
  }
}

// ---------------------------------------------------------------------------
__global__ __launch_bounds__(256, 2)
void dmoe_main(const float* __restrict__ x,
               const unsigned short* __restrict__ WT,
               const float* __restrict__ b_share,
               const float* __restrict__ b_task,
               const float* __restrict__ b_gate,
               float* __restrict__ out) {
  __shared__ unsigned short xs[BM * 264];   // 33792 B, padded rows
  __shared__ float gates[BM * 16];          // softmaxed gate weights

  const int tid  = threadIdx.x;
  const int lane = tid & 63;
  const int wave = tid >> 6;       // 0..3
  const int col  = lane & 15;      // MFMA m/n index
  const int quad = lane >> 4;      // 0..3 (k-chunk / row-group)
  const int blk  = blockIdx.x;

  // ---- stage x tile -> LDS bf16 (row stride 264 elems) ----
  {
    const float4* x4 = (const float4*)(x + (size_t)blk * BM * 256);
    #pragma unroll
    for (int it = 0; it < 16; ++it) {
      int i   = it * 256 + tid;    // 0..4095
      int row = i >> 6;
      int c4  = i & 63;
      float4 v = x4[row * 64 + c4];
      unsigned lo = (unsigned)f2bf(v.x) | ((unsigned)f2bf(v.y) << 16);
      unsigned hi = (unsigned)f2bf(v.z) | ((unsigned)f2bf(v.w) << 16);
      unsigned long long p = ((unsigned long long)hi << 32) | lo;
      *(unsigned long long*)&xs[row * 264 + c4 * 4] = p;
    }
  }
  __syncthreads();

  // ---- gates: wave w computes rows [16w, 16w+16), all 16 logit cols ----
  {
    const unsigned short* wg = WT + 12 * 32768;   // [16][256]
    short8 a[8], b[8];
    const unsigned short* ap = &xs[(wave * 16 + col) * 264 + quad * 8];
    const unsigned short* bp = wg + col * 256 + quad * 8;
    #pragma unroll
    for (int kk = 0; kk < 8; ++kk) {
      a[kk] = *(const short8*)(ap + kk * 32);
      b[kk] = *(const short8*)(bp + kk * 32);
    }
    float4v acc = {0.f, 0.f, 0.f, 0.f};
    #pragma unroll
    for (int kk = 0; kk < 8; ++kk)
      acc = __builtin_amdgcn_mfma_f32_16x16x32_bf16(a[kk], b[kk], acc, 0, 0, 0);
    float bg = b_gate[col];
    #pragma unroll
    for (int r = 0; r < 4; ++r) {
      float v = acc[r] + bg;
      // softmax over 8 gate cols: lanes grouped by (quad, col>>3)
      float m = v;
      m = fmaxf(m, __shfl_xor(m, 1));
      m = fmaxf(m, __shfl_xor(m, 2));
      m = fmaxf(m, __shfl_xor(m, 4));
      float p = __expf(v - m);
      float s = p;
      s += __shfl_xor(s, 1);
      s += __shfl_xor(s, 2);
      s += __shfl_xor(s, 4);
      int row = wave * 16 + quad * 4 + r;
      gates[row * 16 + col] = p / s;
    }
  }
  __syncthreads();

  // ---- main loop: 12 experts, wave owns h-slice [32*wave, 32*wave+32) ----
  const int hb = wave * 32;
  float tw[2][4][2][4];   // [task][chunk][ntile][r]
  #pragma unroll
  for (int t = 0; t < 2; ++t)
    #pragma unroll
    for (int c = 0; c < 4; ++c)
      #pragma unroll
      for (int nt = 0; nt < 2; ++nt)
        #pragma unroll
        for (int r = 0; r < 4; ++r)
          tw[t][c][nt][r] = 0.f;

  #pragma unroll 1
  for (int e = 0; e < 12; ++e) {
    // B-fragments: wave's 32-wide h-slice of expert e (L2-hot, 16 KB/wave)
    short8 bf[2][8];
    const unsigned short* wtE = WT + (size_t)e * 32768;
    #pragma unroll
    for (int nt = 0; nt < 2; ++nt) {
      const unsigned short* bp = wtE + (hb + nt * 16 + col) * 256 + quad * 8;
      #pragma unroll
      for (int kk = 0; kk < 8; ++kk)
        bf[nt][kk] = *(const short8*)(bp + kk * 32);
    }
    const float* bptr = (e < 4) ? (b_share + e * 128) : (b_task + (e - 4) * 128);
    float bias0 = bptr[hb + col];
    float bias1 = bptr[hb + 16 + col];

    #pragma unroll
    for (int c = 0; c < 4; ++c) {
      short8 a[8];
      const unsigned short* ap = &xs[(c * 16 + col) * 264 + quad * 8];
      #pragma unroll
      for (int kk = 0; kk < 8; ++kk)
        a[kk] = *(const short8*)(ap + kk * 32);
      float4v acc0 = {0.f, 0.f, 0.f, 0.f};
      float4v acc1 = {0.f, 0.f, 0.f, 0.f};
      #pragma unroll
      for (int kk = 0; kk < 8; ++kk) {
        acc0 = __builtin_amdgcn_mfma_f32_16x16x32_bf16(a[kk], bf[0][kk], acc0, 0, 0, 0);
        acc1 = __builtin_amdgcn_mfma_f32_16x16x32_bf16(a[kk], bf[1][kk], acc1, 0, 0, 0);
      }
      #pragma unroll
      for (int r = 0; r < 4; ++r) {
        int row = c * 16 + quad * 4 + r;
        float v0 = fmaxf(acc0[r] + bias0, 0.f);
        float v1 = fmaxf(acc1[r] + bias1, 0.f);
        if (e < 4) {
          // shared expert e feeds both tasks; gate cols e and 8+e
          float ga = gates[row * 16 + e];
          float gb = gates[row * 16 + 8 + e];
          tw[0][c][0][r] += ga * v0;
          tw[0][c][1][r] += ga * v1;
          tw[1][c][0][r] += gb * v0;
          tw[1][c][1][r] += gb * v1;
        } else {
          int t = (e - 4) >> 2;
          int g = t * 8 + 4 + ((e - 4) & 3);
          float gv = gates[row * 16 + g];
          if (t == 0) {
            tw[0][c][0][r] += gv * v0;
            tw[0][c][1][r] += gv * v1;
          } else {
            tw[1][c][0][r] += gv * v0;
            tw[1][c][1][r] += gv * v1;
          }
        }
      }
    }
  }

  // ---- write towers: out[t][row][h], t-stride = 32768*128 = 1<<22 ----
  #pragma unroll
  for (int t = 0; t < 2; ++t)
    #pragma unroll
    for (int c = 0; c < 4; ++c)
      #pragma unroll
      for (int nt = 0; nt < 2; ++nt)
        #pragma unroll
        for (int r = 0; r < 4; ++r) {
          int row = blk * BM + c * 16 + quad * 4 + r;
          int h   = hb + nt * 16 + col;
          out[((size_t)t << 22) + (size_t)row * 128 + h] = tw[t][c][nt][r];
        }
}

// ---------------------------------------------------------------------------
extern "C" void kernel_launch(void* const* d_in, const int* in_sizes, int n_in,
                              void* d_out, int out_size, void* d_ws, size_t ws_size,
                              hipStream_t stream) {
  const float* x       = (const float*)d_in[0];
  const float* W_share = (const float*)d_in[1];
  const float* b_share = (const float*)d_in[2];
  const float* W_task  = (const float*)d_in[3];
  const float* b_task  = (const float*)d_in[4];
  const float* W_gate  = (const float*)d_in[5];
  const float* b_gate  = (const float*)d_in[6];
  float* out = (float*)d_out;
  unsigned short* WT = (unsigned short*)d_ws;   // 397312 bf16 = 794624 B

  prep_kernel<<<1552, 256, 0, stream>>>(W_share, W_task, W_gate, WT);
  dmoe_main<<<512, 256, 0, stream>>>(x, WT, b_share, b_task, b_gate, out);
}